// Round 9
// baseline (332.657 us; speedup 1.0000x reference)
//
#include <hip/hip_runtime.h>
#include <math.h>

#define Hdim 4096
#define NE 256
#define BM 32
#define BK 32
#define NKC (Hdim / BK)          // 128 K-chunks
#define PLANE_ELEMS (Hdim * NE)  // f16 elements per plane (1,048,576 = 2 MB)
#define PLANE_BYTES (PLANE_ELEMS * 2)

// Scales (exact powers of two; undone in epilogue):
//   W' = 64*w, X' = 16*x, m-planes additionally *2048.
//   logit = (acc0 + acc1*2^-11) * 2^-10   (mm product dropped: validated R6-R8)
#define C0 9.765625e-4f            // 2^-10
#define C1 4.76837158203125e-7f    // 2^-21

typedef _Float16 f16x8 __attribute__((ext_vector_type(8)));
typedef float f32x4 __attribute__((ext_vector_type(4)));

__device__ __forceinline__ void gload_lds16(const void* g, void* l) {
  __builtin_amdgcn_global_load_lds((const __attribute__((address_space(1))) void*)g,
                                   (__attribute__((address_space(3))) void*)l, 16, 0, 0);
}

// ---------------------------------------------------------------------------
// W [256][4096] fp32 -> 2 f16 planes: h = f16(64w), m = f16((64w - h)*2048).
// Plane layout: [k8 0..511][n 0..255] chunks of 8 f16 (16 B): element (n,k)
// at plane + ((k/8)*256 + n)*8 + k%8 — the exact LDS image staged per chunk.
// ---------------------------------------------------------------------------
__global__ __launch_bounds__(256)
void convert_w(const float* __restrict__ W, _Float16* __restrict__ pl) {
  const int id = blockIdx.x * 256 + threadIdx.x;  // 0 .. 131071
  const int k8 = id & 511;
  const int n = id >> 9;
  const float* src = W + (long)n * Hdim + k8 * 8;
  const float4 x0 = *(const float4*)src;
  const float4 x1 = *(const float4*)(src + 4);
  const float xv[8] = {x0.x, x0.y, x0.z, x0.w, x1.x, x1.y, x1.z, x1.w};
  f16x8 vh, vm;
#pragma unroll
  for (int j = 0; j < 8; ++j) {
    const float v = xv[j] * 64.f;
    const _Float16 h = (_Float16)v;
    const float r = (v - (float)h) * 2048.f;
    vh[j] = h;
    vm[j] = (_Float16)r;
  }
  const long co = ((long)k8 * NE + n) * 8;
  *(f16x8*)(pl + co) = vh;
  *(f16x8*)(pl + PLANE_ELEMS + co) = vm;
}

// ---------------------------------------------------------------------------
// Fused: logits = X @ W^T via 3-product split-f16 MFMA (hh, hm, mh), then
// top-k epilogue. R8-verified structure (W dbuf LDS via global_load_lds +
// __syncthreads, 512 thr = 8 waves x (32 tok x 32 exp), K-stagger, 2 blk/CU)
// with ONE change: X (A-operand) never touches LDS. Each lane loads its own
// A-fragment source fp32 directly from global (row bm0+fm*16+r16, cols
// kc*32+c4*8..+7; the 4 KB X chunk is L1-resident so the 8-wave overlap is
// a broadcast) and converts in-register (CVT8). Removes the 8-way-duplicated
// af ds_reads (-50% LDS read traffic) and all X ds_writes. LDS 64 KB.
// ---------------------------------------------------------------------------
__global__ __launch_bounds__(512, 4)
void moe_gate_fused(const float* __restrict__ X, const _Float16* __restrict__ pl,
                    const float* __restrict__ bias, float* __restrict__ out, int T) {
  __shared__ __align__(16) unsigned char smem[65536];
  const int tid = threadIdx.x;
  const int lane = tid & 63, wave = tid >> 6;      // wave = wn (0..7)
  const int r16 = lane & 15, c4 = lane >> 4;
  const long bm0 = (long)blockIdx.x * BM;
  // K-ring start: differs for both (b,b+1) and (b,b+256) co-residency
  const int sblk = (((blockIdx.x >> 8) ^ blockIdx.x) & 1) * (NKC / 2);

  f32x4 acc0[2][2], acc1[2][2];
#pragma unroll
  for (int i = 0; i < 2; ++i)
#pragma unroll
    for (int j = 0; j < 2; ++j) {
      acc0[i][j] = (f32x4)(0.f);
      acc1[i][j] = (f32x4)(0.f);
    }

  // per-lane A-fragment source rows: fm=0 -> row bm0+r16, fm=1 -> +16
  const float* xr0 = X + (bm0 + r16) * (long)Hdim + c4 * 8;
  const float* xr1 = xr0 + 16 * (long)Hdim;

  float4 xc0, xc1, xc2, xc3, xn0, xn1, xn2, xn3;

#define STAGE_W(b, kc)                                                          \
  {                                                                             \
    _Pragma("unroll") for (int p = 0; p < 2; ++p)                               \
        _Pragma("unroll") for (int i = 0; i < 2; ++i) {                         \
      const char* g = (const char*)pl + (size_t)p * PLANE_BYTES +               \
                      (size_t)(kc) * 16384 + (size_t)(i * 512 + tid) * 16;      \
      void* l = (void*)&smem[(b) * 32768 + p * 16384 +                          \
                             (i * 512 + (tid & ~63)) * 16];                     \
      gload_lds16(g, l);                                                        \
    }                                                                           \
  }

#define LOADX(kc_)                                                              \
  {                                                                             \
    const size_t o = (size_t)(kc_) * BK;                                        \
    xn0 = *(const float4*)(xr0 + o);                                            \
    xn1 = *(const float4*)(xr0 + o + 4);                                        \
    xn2 = *(const float4*)(xr1 + o);                                            \
    xn3 = *(const float4*)(xr1 + o + 4);                                        \
  }

#define CVT8(dsth, dstm, va, vb)                                                \
  {                                                                             \
    const float xv_[8] = {(va).x, (va).y, (va).z, (va).w,                       \
                          (vb).x, (vb).y, (vb).z, (vb).w};                      \
    _Pragma("unroll") for (int j = 0; j < 8; ++j) {                             \
      const float v = xv_[j] * 16.f;                                            \
      const _Float16 h = (_Float16)v;                                           \
      const float r = (v - (float)h) * 2048.f;                                  \
      (dsth)[j] = h;                                                            \
      (dstm)[j] = (_Float16)r;                                                  \
    }                                                                           \
  }

#define COMPUTE(b)                                                              \
  {                                                                             \
    const int wof = (b) * 32768;                                                \
    f16x8 af[2][2], bfr[2][2];                                                  \
    CVT8(af[0][0], af[1][0], xc0, xc1);                                         \
    CVT8(af[0][1], af[1][1], xc2, xc3);                                         \
    _Pragma("unroll") for (int p = 0; p < 2; ++p)                               \
        _Pragma("unroll") for (int fn = 0; fn < 2; ++fn)                        \
            bfr[p][fn] = *(const f16x8*)&smem[wof + p * 16384 +                 \
                                              (c4 * 256 +                      \
                                               (wave * 32 + fn * 16 + r16)) *  \
                                                  16];                          \
    _Pragma("unroll") for (int fm = 0; fm < 2; ++fm)                            \
        _Pragma("unroll") for (int fn = 0; fn < 2; ++fn) {                      \
      acc0[fm][fn] = __builtin_amdgcn_mfma_f32_16x16x32_f16(                    \
          af[0][fm], bfr[0][fn], acc0[fm][fn], 0, 0, 0);                        \
      f32x4 s = acc1[fm][fn];                                                   \
      s = __builtin_amdgcn_mfma_f32_16x16x32_f16(af[0][fm], bfr[1][fn], s, 0, 0, 0); \
      s = __builtin_amdgcn_mfma_f32_16x16x32_f16(af[1][fm], bfr[0][fn], s, 0, 0, 0); \
      acc1[fm][fn] = s;                                                         \
    }                                                                           \
  }

  // prologue: stagger-start chunk — X into regs, W into buffer 0
  {
    const size_t o = (size_t)sblk * BK;
    xc0 = *(const float4*)(xr0 + o);
    xc1 = *(const float4*)(xr0 + o + 4);
    xc2 = *(const float4*)(xr1 + o);
    xc3 = *(const float4*)(xr1 + o + 4);
  }
  STAGE_W(0, sblk);
  __syncthreads();

  for (int i = 0; i < NKC; ++i) {
    const int cb = i & 1;
    const bool more = (i + 1 < NKC);
    const int kn = (i + 1 + sblk) & (NKC - 1);
    if (more) {
      STAGE_W(cb ^ 1, kn);
      LOADX(kn);  // issue early (T14); lands in xn regs during COMPUTE
    }
    COMPUTE(cb);
    if (more) { xc0 = xn0; xc1 = xn1; xc2 = xn2; xc3 = xn3; }
    __syncthreads();
  }

  // ---- epilogue: logits -> LDS [32][260] fp32, then fused top-k ----
  float* lg = (float*)smem;
#pragma unroll
  for (int fm = 0; fm < 2; ++fm)
#pragma unroll
    for (int fn = 0; fn < 2; ++fn)
#pragma unroll
      for (int r = 0; r < 4; ++r) {
        const int t = fm * 16 + c4 * 4 + r;
        const int n = wave * 32 + fn * 16 + r16;
        lg[t * 260 + n] = fmaf(acc1[fm][fn][r], C1, acc0[fm][fn][r] * C0);
      }
  __syncthreads();

  // phase 2 (verified rounds 1-8 logic): wave processes 4 tokens sequentially
  const float4 bv = *(const float4*)(bias + lane * 4);
  for (int i = 0; i < 4; ++i) {
    const int t = wave * 4 + i;
    const float4 lgv = *(const float4*)&lg[t * 260 + lane * 4];

    const float s0 = 1.f / (1.f + expf(-lgv.x));
    const float s1 = 1.f / (1.f + expf(-lgv.y));
    const float s2 = 1.f / (1.f + expf(-lgv.z));
    const float s3 = 1.f / (1.f + expf(-lgv.w));

    const float c0 = s0 + bv.x, c1 = s1 + bv.y, c2 = s2 + bv.z, c3 = s3 + bv.w;

    // lane-local top2 of 4
    float m1 = fmaxf(c0, c1), m2 = fminf(c0, c1);
    if (c2 > m1) { m2 = m1; m1 = c2; } else m2 = fmaxf(m2, c2);
    if (c3 > m1) { m2 = m1; m1 = c3; } else m2 = fmaxf(m2, c3);
#pragma unroll
    for (int off = 1; off < 8; off <<= 1) {
      const float o1 = __shfl_xor(m1, off);
      const float o2 = __shfl_xor(m2, off);
      if (o1 > m1) { m2 = fmaxf(m1, o2); m1 = o1; }
      else m2 = fmaxf(m2, o1);
    }
    const float gs = m1 + m2;  // group score (identical across the 8 lanes)

    const int gme = lane >> 3;
    int rank = 0;
#pragma unroll
    for (int j = 0; j < 8; ++j) {
      const float gj = __shfl(gs, j * 8);
      rank += ((gj > gs) || (gj == gs && j < gme)) ? 1 : 0;
    }
    const bool sel = rank < 4;

    const float NEG = -INFINITY;
    float q0 = sel ? c0 : NEG, q1 = sel ? c1 : NEG;
    float q2 = sel ? c2 : NEG, q3 = sel ? c3 : NEG;

    float sum = 0.f;
    int my_e = 0;
    float my_w = 0.f;
#pragma unroll
    for (int r = 0; r < 8; ++r) {
      float v = q0; int ix = 0;
      if (q1 > v) { v = q1; ix = 1; }
      if (q2 > v) { v = q2; ix = 2; }
      if (q3 > v) { v = q3; ix = 3; }
      int e = lane * 4 + ix;
#pragma unroll
      for (int off = 1; off < 64; off <<= 1) {
        const float v2 = __shfl_xor(v, off);
        const int e2 = __shfl_xor(e, off);
        const bool take = (v2 > v) || (v2 == v && e2 < e);
        v = take ? v2 : v;
        e = take ? e2 : e;
      }
      const int slot = e & 3, owner = e >> 2;
      const float svs = (slot == 0) ? s0 : ((slot == 1) ? s1 : ((slot == 2) ? s2 : s3));
      const float wgt = __shfl(svs, owner);
      sum += wgt;
      if (lane == r) { my_e = e; my_w = wgt; }
      const bool own = (lane == owner);
      q0 = (own && slot == 0) ? NEG : q0;
      q1 = (own && slot == 1) ? NEG : q1;
      q2 = (own && slot == 2) ? NEG : q2;
      q3 = (own && slot == 3) ? NEG : q3;
    }

    if (lane < 8) {
      const float denom = sum + 1e-20f;
      const long tg = bm0 + t;
      out[tg * 8 + lane] = (float)my_e;
      out[(long)T * 8 + tg * 8 + lane] = my_w / denom * 2.5f;
    }
  }
}

// ---------------------------------------------------------------------------
extern "C" void kernel_launch(void* const* d_in, const int* in_sizes, int n_in,
                              void* d_out, int out_size, void* d_ws, size_t ws_size,
                              hipStream_t stream) {
  const float* X = (const float*)d_in[0];   // [T, 4096]
  const float* W = (const float*)d_in[1];   // [256, 4096]
  const float* B = (const float*)d_in[2];   // [256]
  float* out = (float*)d_out;
  const int T = in_sizes[0] / Hdim;         // 16384

  _Float16* planes = (_Float16*)d_ws;       // 2 x 2 MB = 4 MB scratch

  convert_w<<<512, 256, 0, stream>>>(W, planes);
  moe_gate_fused<<<T / BM, 512, 0, stream>>>(X, planes, B, out, T);
}

// Round 10
// 195.032 us; speedup vs baseline: 1.7057x; 1.7057x over previous
//
#include <hip/hip_runtime.h>
#include <math.h>

#define Hdim 4096
#define NE 256
#define BM 32
#define BK 32
#define NKC (Hdim / BK)          // 128 K-chunks
#define PLANE_ELEMS (Hdim * NE)  // f16 elements per plane (1,048,576 = 2 MB)
#define PLANE_BYTES (PLANE_ELEMS * 2)

// Scales (exact powers of two; undone in epilogue):
//   W' = 64*w, X' = 16*x, m-planes additionally *2048.
//   logit = (acc0 + acc1*2^-11) * 2^-10   (mm product dropped: validated R6-R8)
#define C0 9.765625e-4f            // 2^-10
#define C1 4.76837158203125e-7f    // 2^-21

typedef _Float16 f16x8 __attribute__((ext_vector_type(8)));
typedef _Float16 f16x4 __attribute__((ext_vector_type(4)));
typedef float f32x4 __attribute__((ext_vector_type(4)));

__device__ __forceinline__ void gload_lds16(const void* g, void* l) {
  __builtin_amdgcn_global_load_lds((const __attribute__((address_space(1))) void*)g,
                                   (__attribute__((address_space(3))) void*)l, 16, 0, 0);
}

// ---------------------------------------------------------------------------
// W [256][4096] fp32 -> 2 f16 planes: h = f16(64w), m = f16((64w - h)*2048).
// Plane layout: [k8 0..511][n 0..255] chunks of 8 f16 (16 B): element (n,k)
// at plane + ((k/8)*256 + n)*8 + k%8 — the exact LDS image staged per chunk.
// ---------------------------------------------------------------------------
__global__ __launch_bounds__(256)
void convert_w(const float* __restrict__ W, _Float16* __restrict__ pl) {
  const int id = blockIdx.x * 256 + threadIdx.x;  // 0 .. 131071
  const int k8 = id & 511;
  const int n = id >> 9;
  const float* src = W + (long)n * Hdim + k8 * 8;
  const float4 x0 = *(const float4*)src;
  const float4 x1 = *(const float4*)(src + 4);
  const float xv[8] = {x0.x, x0.y, x0.z, x0.w, x1.x, x1.y, x1.z, x1.w};
  f16x8 vh, vm;
#pragma unroll
  for (int j = 0; j < 8; ++j) {
    const float v = xv[j] * 64.f;
    const _Float16 h = (_Float16)v;
    const float r = (v - (float)h) * 2048.f;
    vh[j] = h;
    vm[j] = (_Float16)r;
  }
  const long co = ((long)k8 * NE + n) * 8;
  *(f16x8*)(pl + co) = vh;
  *(f16x8*)(pl + PLANE_ELEMS + co) = vm;
}

// ---------------------------------------------------------------------------
// Fused: logits = X @ W^T via 3-product split-f16 MFMA (hh, hm, mh), then
// top-k epilogue. R8-verified structure (W dbuf LDS via global_load_lds +
// __syncthreads, 512 thr = 8 waves x (32 tok x 32 exp), K-stagger, 2 blk/CU,
// 16 waves/CU) + T19 sched_group_barrier: emit per chunk
// {4 ds_read, 4 MFMA, 4 ds_read, 8 MFMA} so LDS read bursts are split around
// the first MFMA cluster and the two co-resident blocks' LDS bursts
// statistically interleave (LDS pipe measured ~50% busy in bursts).
// ---------------------------------------------------------------------------
__global__ __launch_bounds__(512, 4)
void moe_gate_fused(const float* __restrict__ X, const _Float16* __restrict__ pl,
                    const float* __restrict__ bias, float* __restrict__ out, int T) {
  __shared__ __align__(16) unsigned char smem[73728];
  const int tid = threadIdx.x;
  const int lane = tid & 63, wave = tid >> 6;      // wave = wn (0..7)
  const int r16 = lane & 15, c4 = lane >> 4;
  const long bm0 = (long)blockIdx.x * BM;
  // K-ring start: differs for both (b,b+1) and (b,b+256) co-residency
  const int sblk = (((blockIdx.x >> 8) ^ blockIdx.x) & 1) * (NKC / 2);

  f32x4 acc0[2][2], acc1[2][2];
#pragma unroll
  for (int i = 0; i < 2; ++i)
#pragma unroll
    for (int j = 0; j < 2; ++j) {
      acc0[i][j] = (f32x4)(0.f);
      acc1[i][j] = (f32x4)(0.f);
    }

  // X staging geometry: first 256 threads -> (token xm 0..31, f4-slot xf 0..7)
  const int xm = tid >> 3;
  const int xf = tid & 7;
  const float* xsrc = X + (bm0 + xm) * (long)Hdim + xf * 4;
  const int xws = ((xf >> 1) * 32 + xm) * 16 + (xf & 1) * 8;  // within one plane

#define STAGE_W(b, kc)                                                          \
  {                                                                             \
    _Pragma("unroll") for (int p = 0; p < 2; ++p)                               \
        _Pragma("unroll") for (int i = 0; i < 2; ++i) {                         \
      const char* g = (const char*)pl + (size_t)p * PLANE_BYTES +               \
                      (size_t)(kc) * 16384 + (size_t)(i * 512 + tid) * 16;      \
      void* l = (void*)&smem[(b) * 32768 + p * 16384 +                          \
                             (i * 512 + (tid & ~63)) * 16];                     \
      gload_lds16(g, l);                                                        \
    }                                                                           \
  }

#define WRITE_X(b, xr)                                                          \
  if (tid < 256) {                                                              \
    f16x4 vh, vm;                                                               \
    const float xa[4] = {(xr).x, (xr).y, (xr).z, (xr).w};                       \
    _Pragma("unroll") for (int j = 0; j < 4; ++j) {                             \
      const float v = xa[j] * 16.f;                                             \
      const _Float16 h = (_Float16)v;                                           \
      const float r = (v - (float)h) * 2048.f;                                  \
      vh[j] = h;                                                                \
      vm[j] = (_Float16)r;                                                      \
    }                                                                           \
    const int xo = 65536 + (b) * 4096;                                          \
    *(f16x4*)&smem[xo + 0 * 2048 + xws] = vh;                                   \
    *(f16x4*)&smem[xo + 1 * 2048 + xws] = vm;                                   \
  }

#define COMPUTE(b)                                                              \
  {                                                                             \
    const int wof = (b) * 32768;                                                \
    const int xo = 65536 + (b) * 4096;                                          \
    f16x8 af[2][2], bfr[2][2];                                                  \
    _Pragma("unroll") for (int p = 0; p < 2; ++p) {                             \
      _Pragma("unroll") for (int fm = 0; fm < 2; ++fm)                          \
          af[p][fm] = *(const f16x8*)&smem[xo + p * 2048 +                      \
                                           (c4 * 32 + fm * 16 + r16) * 16];     \
      _Pragma("unroll") for (int fn = 0; fn < 2; ++fn)                          \
          bfr[p][fn] = *(const f16x8*)&smem[wof + p * 16384 +                   \
                                            (c4 * 256 +                        \
                                             (wave * 32 + fn * 16 + r16)) * 16];\
    }                                                                           \
    _Pragma("unroll") for (int fm = 0; fm < 2; ++fm)                            \
        _Pragma("unroll") for (int fn = 0; fn < 2; ++fn) {                      \
      acc0[fm][fn] = __builtin_amdgcn_mfma_f32_16x16x32_f16(                    \
          af[0][fm], bfr[0][fn], acc0[fm][fn], 0, 0, 0);                        \
      f32x4 s = acc1[fm][fn];                                                   \
      s = __builtin_amdgcn_mfma_f32_16x16x32_f16(af[0][fm], bfr[1][fn], s, 0, 0, 0); \
      s = __builtin_amdgcn_mfma_f32_16x16x32_f16(af[1][fm], bfr[0][fn], s, 0, 0, 0); \
      acc1[fm][fn] = s;                                                         \
    }                                                                           \
    /* T19: interleave LDS reads with MFMA clusters (DS_READ=0x100, MFMA=0x8) */\
    __builtin_amdgcn_sched_group_barrier(0x100, 4, 0);                          \
    __builtin_amdgcn_sched_group_barrier(0x008, 4, 0);                          \
    __builtin_amdgcn_sched_group_barrier(0x100, 4, 0);                          \
    __builtin_amdgcn_sched_group_barrier(0x008, 8, 0);                          \
  }

  // prologue: stagger-start chunk into buffer 0
  STAGE_W(0, sblk);
  {
    const float4 x0 = (tid < 256) ? *(const float4*)(xsrc + (size_t)sblk * BK)
                                  : make_float4(0.f, 0.f, 0.f, 0.f);
    WRITE_X(0, x0);
  }
  __syncthreads();

  for (int i = 0; i < NKC; ++i) {
    const int cb = i & 1;
    float4 xn = make_float4(0.f, 0.f, 0.f, 0.f);
    const bool more = (i + 1 < NKC);
    const int kn = (i + 1 + sblk) & (NKC - 1);
    if (more) {
      STAGE_W(cb ^ 1, kn);
      if (tid < 256) xn = *(const float4*)(xsrc + (size_t)kn * BK);  // early
    }
    COMPUTE(cb);
    if (more) WRITE_X(cb ^ 1, xn);  // write late, after compute
    __syncthreads();
  }

  // ---- epilogue: logits -> LDS [32][260] fp32, then fused top-k ----
  float* lg = (float*)smem;
#pragma unroll
  for (int fm = 0; fm < 2; ++fm)
#pragma unroll
    for (int fn = 0; fn < 2; ++fn)
#pragma unroll
      for (int r = 0; r < 4; ++r) {
        const int t = fm * 16 + c4 * 4 + r;
        const int n = wave * 32 + fn * 16 + r16;
        lg[t * 260 + n] = fmaf(acc1[fm][fn][r], C1, acc0[fm][fn][r] * C0);
      }
  __syncthreads();

  // phase 2 (verified rounds 1-8 logic): wave processes 4 tokens sequentially
  const float4 bv = *(const float4*)(bias + lane * 4);
  for (int i = 0; i < 4; ++i) {
    const int t = wave * 4 + i;
    const float4 lgv = *(const float4*)&lg[t * 260 + lane * 4];

    const float s0 = 1.f / (1.f + expf(-lgv.x));
    const float s1 = 1.f / (1.f + expf(-lgv.y));
    const float s2 = 1.f / (1.f + expf(-lgv.z));
    const float s3 = 1.f / (1.f + expf(-lgv.w));

    const float c0 = s0 + bv.x, c1 = s1 + bv.y, c2 = s2 + bv.z, c3 = s3 + bv.w;

    // lane-local top2 of 4
    float m1 = fmaxf(c0, c1), m2 = fminf(c0, c1);
    if (c2 > m1) { m2 = m1; m1 = c2; } else m2 = fmaxf(m2, c2);
    if (c3 > m1) { m2 = m1; m1 = c3; } else m2 = fmaxf(m2, c3);
#pragma unroll
    for (int off = 1; off < 8; off <<= 1) {
      const float o1 = __shfl_xor(m1, off);
      const float o2 = __shfl_xor(m2, off);
      if (o1 > m1) { m2 = fmaxf(m1, o2); m1 = o1; }
      else m2 = fmaxf(m2, o1);
    }
    const float gs = m1 + m2;  // group score (identical across the 8 lanes)

    const int gme = lane >> 3;
    int rank = 0;
#pragma unroll
    for (int j = 0; j < 8; ++j) {
      const float gj = __shfl(gs, j * 8);
      rank += ((gj > gs) || (gj == gs && j < gme)) ? 1 : 0;
    }
    const bool sel = rank < 4;

    const float NEG = -INFINITY;
    float q0 = sel ? c0 : NEG, q1 = sel ? c1 : NEG;
    float q2 = sel ? c2 : NEG, q3 = sel ? c3 : NEG;

    float sum = 0.f;
    int my_e = 0;
    float my_w = 0.f;
#pragma unroll
    for (int r = 0; r < 8; ++r) {
      float v = q0; int ix = 0;
      if (q1 > v) { v = q1; ix = 1; }
      if (q2 > v) { v = q2; ix = 2; }
      if (q3 > v) { v = q3; ix = 3; }
      int e = lane * 4 + ix;
#pragma unroll
      for (int off = 1; off < 64; off <<= 1) {
        const float v2 = __shfl_xor(v, off);
        const int e2 = __shfl_xor(e, off);
        const bool take = (v2 > v) || (v2 == v && e2 < e);
        v = take ? v2 : v;
        e = take ? e2 : e;
      }
      const int slot = e & 3, owner = e >> 2;
      const float svs = (slot == 0) ? s0 : ((slot == 1) ? s1 : ((slot == 2) ? s2 : s3));
      const float wgt = __shfl(svs, owner);
      sum += wgt;
      if (lane == r) { my_e = e; my_w = wgt; }
      const bool own = (lane == owner);
      q0 = (own && slot == 0) ? NEG : q0;
      q1 = (own && slot == 1) ? NEG : q1;
      q2 = (own && slot == 2) ? NEG : q2;
      q3 = (own && slot == 3) ? NEG : q3;
    }

    if (lane < 8) {
      const float denom = sum + 1e-20f;
      const long tg = bm0 + t;
      out[tg * 8 + lane] = (float)my_e;
      out[(long)T * 8 + tg * 8 + lane] = my_w / denom * 2.5f;
    }
  }
}

// ---------------------------------------------------------------------------
extern "C" void kernel_launch(void* const* d_in, const int* in_sizes, int n_in,
                              void* d_out, int out_size, void* d_ws, size_t ws_size,
                              hipStream_t stream) {
  const float* X = (const float*)d_in[0];   // [T, 4096]
  const float* W = (const float*)d_in[1];   // [256, 4096]
  const float* B = (const float*)d_in[2];   // [256]
  float* out = (float*)d_out;
  const int T = in_sizes[0] / Hdim;         // 16384

  _Float16* planes = (_Float16*)d_ws;       // 2 x 2 MB = 4 MB scratch

  convert_w<<<512, 256, 0, stream>>>(W, planes);
  moe_gate_fused<<<T / BM, 512, 0, stream>>>(X, planes, B, out, T);
}

// Round 11
// 170.941 us; speedup vs baseline: 1.9460x; 1.1409x over previous
//
#include <hip/hip_runtime.h>
#include <math.h>

#define Hdim 4096
#define NE 256
#define BM 32
#define BK 32
#define NKC (Hdim / BK)          // 128 K-chunks
#define PLANE_ELEMS (Hdim * NE)  // f16 elements per plane (1,048,576 = 2 MB)
#define CHUNK_ELEMS 8192         // f16 elements per K-chunk image (16 KB)

// Scales (exact powers of two; undone in epilogue):
//   W' = 64*w, X' = 16*x, m-planes additionally *2048.
//   logit = (acc0 + acc1*2^-11) * 2^-10   (mm product dropped: validated R6-R10)
#define C0 9.765625e-4f            // 2^-10
#define C1 4.76837158203125e-7f    // 2^-21

typedef _Float16 f16x8 __attribute__((ext_vector_type(8)));
typedef _Float16 f16x4 __attribute__((ext_vector_type(4)));
typedef float f32x4 __attribute__((ext_vector_type(4)));

// ---------------------------------------------------------------------------
// W [256][4096] fp32 -> 2 f16 planes: h = f16(64w), m = f16((64w - h)*2048).
// Plane layout: [k8 0..511][n 0..255] chunks of 8 f16 (16 B): element (n,k)
// at plane + ((k/8)*256 + n)*8 + k%8 — 16 consecutive n are 256 B contiguous,
// so per-lane fragment loads below are coalesced (4 x 256 B per instruction).
// ---------------------------------------------------------------------------
__global__ __launch_bounds__(256)
void convert_w(const float* __restrict__ W, _Float16* __restrict__ pl) {
  const int id = blockIdx.x * 256 + threadIdx.x;  // 0 .. 131071
  const int k8 = id & 511;
  const int n = id >> 9;
  const float* src = W + (long)n * Hdim + k8 * 8;
  const float4 x0 = *(const float4*)src;
  const float4 x1 = *(const float4*)(src + 4);
  const float xv[8] = {x0.x, x0.y, x0.z, x0.w, x1.x, x1.y, x1.z, x1.w};
  f16x8 vh, vm;
#pragma unroll
  for (int j = 0; j < 8; ++j) {
    const float v = xv[j] * 64.f;
    const _Float16 h = (_Float16)v;
    const float r = (v - (float)h) * 2048.f;
    vh[j] = h;
    vm[j] = (_Float16)r;
  }
  const long co = ((long)k8 * NE + n) * 8;
  *(f16x8*)(pl + co) = vh;
  *(f16x8*)(pl + PLANE_ELEMS + co) = vm;
}

// ---------------------------------------------------------------------------
// Fused: logits = X @ W^T via 3-product split-f16 MFMA (hh, hm, mh), then
// top-k epilogue. R8-verified skeleton (X split-f16 staged in dbuf LDS via
// coalesced 256-thread stage + __syncthreads per chunk; 512 thr = 8 waves x
// (32 tok x 32 exp); 2 blk/CU, 16 waves/CU) with ONE change: W fragments are
// loaded DIRECTLY from the ws planes into registers (ping-pong double buffer,
// unroll-2 static indexing), skipping LDS entirely. W is 4 MB -> L2/L3
// resident; the per-lane addresses are the same coalesced pattern
// global_load_lds used. LDS traffic/block-chunk drops 104 KB -> 36 KB.
// LDS 36 KB: X dbuf 2x4 KB @0; epilogue lg [32][260] f32 aliases smem.
// ---------------------------------------------------------------------------
__global__ __launch_bounds__(512, 4)
void moe_gate_fused(const float* __restrict__ X, const _Float16* __restrict__ pl,
                    const float* __restrict__ bias, float* __restrict__ out, int T) {
  __shared__ __align__(16) unsigned char smem[36864];
  const int tid = threadIdx.x;
  const int lane = tid & 63, wave = tid >> 6;      // wave = wn (0..7)
  const int r16 = lane & 15, c4 = lane >> 4;
  const long bm0 = (long)blockIdx.x * BM;

  f32x4 acc0[2][2], acc1[2][2];
#pragma unroll
  for (int i = 0; i < 2; ++i)
#pragma unroll
    for (int j = 0; j < 2; ++j) {
      acc0[i][j] = (f32x4)(0.f);
      acc1[i][j] = (f32x4)(0.f);
    }

  // X staging geometry: first 256 threads -> (token xm 0..31, f4-slot xf 0..7)
  const int xm = tid >> 3;
  const int xf = tid & 7;
  const float* xsrc = X + (bm0 + xm) * (long)Hdim + xf * 4;
  const int xws = ((xf >> 1) * 32 + xm) * 16 + (xf & 1) * 8;  // within one plane

  // per-lane W-fragment sources (chunk image offset (c4*256 + n)*8, n = wave*32+fn*16+r16)
  const _Float16* wsrc0 = pl + ((size_t)(c4 * 256 + wave * 32 + r16)) * 8;
  const _Float16* wsrc1 = wsrc0 + PLANE_ELEMS;

  f16x8 wA[2][2], wB[2][2];   // [plane][fn]

#define LOADW(dst, kc_)                                                         \
  {                                                                             \
    const size_t ko = (size_t)(kc_) * CHUNK_ELEMS;                              \
    _Pragma("unroll") for (int fn = 0; fn < 2; ++fn) {                          \
      dst[0][fn] = *(const f16x8*)(wsrc0 + ko + fn * 128);                      \
      dst[1][fn] = *(const f16x8*)(wsrc1 + ko + fn * 128);                      \
    }                                                                           \
  }

#define WRITE_X(b, xr)                                                          \
  if (tid < 256) {                                                              \
    f16x4 vh, vm;                                                               \
    const float xa[4] = {(xr).x, (xr).y, (xr).z, (xr).w};                       \
    _Pragma("unroll") for (int j = 0; j < 4; ++j) {                             \
      const float v = xa[j] * 16.f;                                             \
      const _Float16 h = (_Float16)v;                                           \
      const float r = (v - (float)h) * 2048.f;                                  \
      vh[j] = h;                                                                \
      vm[j] = (_Float16)r;                                                      \
    }                                                                           \
    const int xo = (b) * 4096;                                                  \
    *(f16x4*)&smem[xo + 0 * 2048 + xws] = vh;                                   \
    *(f16x4*)&smem[xo + 1 * 2048 + xws] = vm;                                   \
  }

#define COMPUTE(b, wreg)                                                        \
  {                                                                             \
    const int xo = (b) * 4096;                                                  \
    f16x8 af[2][2];                                                             \
    _Pragma("unroll") for (int p = 0; p < 2; ++p)                               \
        _Pragma("unroll") for (int fm = 0; fm < 2; ++fm)                        \
            af[p][fm] = *(const f16x8*)&smem[xo + p * 2048 +                    \
                                             (c4 * 32 + fm * 16 + r16) * 16];   \
    _Pragma("unroll") for (int fm = 0; fm < 2; ++fm)                            \
        _Pragma("unroll") for (int fn = 0; fn < 2; ++fn) {                      \
      acc0[fm][fn] = __builtin_amdgcn_mfma_f32_16x16x32_f16(                    \
          af[0][fm], wreg[0][fn], acc0[fm][fn], 0, 0, 0);                       \
      f32x4 s = acc1[fm][fn];                                                   \
      s = __builtin_amdgcn_mfma_f32_16x16x32_f16(af[0][fm], wreg[1][fn], s, 0, 0, 0); \
      s = __builtin_amdgcn_mfma_f32_16x16x32_f16(af[1][fm], wreg[0][fn], s, 0, 0, 0); \
      acc1[fm][fn] = s;                                                         \
    }                                                                           \
  }

  // prologue: X chunk 0 into LDS buf 0, W chunk 0 into wA
  {
    const float4 x0 = (tid < 256) ? *(const float4*)(xsrc)
                                  : make_float4(0.f, 0.f, 0.f, 0.f);
    WRITE_X(0, x0);
  }
  LOADW(wA, 0);
  __syncthreads();

  for (int kc = 0; kc < NKC; kc += 2) {
    {  // even chunk kc: compute (buf0, wA); prefetch kc+1 (always valid)
      float4 xn = make_float4(0.f, 0.f, 0.f, 0.f);
      if (tid < 256) xn = *(const float4*)(xsrc + (size_t)(kc + 1) * BK);
      LOADW(wB, kc + 1);
      COMPUTE(0, wA);
      WRITE_X(1, xn);
      __syncthreads();
    }
    {  // odd chunk kc+1: compute (buf1, wB); prefetch kc+2 (clamped tail)
      const int k2 = (kc + 2 < NKC) ? kc + 2 : NKC - 1;
      float4 xn = make_float4(0.f, 0.f, 0.f, 0.f);
      if (tid < 256) xn = *(const float4*)(xsrc + (size_t)k2 * BK);
      LOADW(wA, k2);
      COMPUTE(1, wB);
      if (kc + 2 < NKC) WRITE_X(0, xn);
      __syncthreads();
    }
  }

  // ---- epilogue: logits -> LDS [32][260] fp32, then fused top-k ----
  float* lg = (float*)smem;
#pragma unroll
  for (int fm = 0; fm < 2; ++fm)
#pragma unroll
    for (int fn = 0; fn < 2; ++fn)
#pragma unroll
      for (int r = 0; r < 4; ++r) {
        const int t = fm * 16 + c4 * 4 + r;
        const int n = wave * 32 + fn * 16 + r16;
        lg[t * 260 + n] = fmaf(acc1[fm][fn][r], C1, acc0[fm][fn][r] * C0);
      }
  __syncthreads();

  // phase 2 (verified rounds 1-10 logic): wave processes 4 tokens sequentially
  const float4 bv = *(const float4*)(bias + lane * 4);
  for (int i = 0; i < 4; ++i) {
    const int t = wave * 4 + i;
    const float4 lgv = *(const float4*)&lg[t * 260 + lane * 4];

    const float s0 = 1.f / (1.f + expf(-lgv.x));
    const float s1 = 1.f / (1.f + expf(-lgv.y));
    const float s2 = 1.f / (1.f + expf(-lgv.z));
    const float s3 = 1.f / (1.f + expf(-lgv.w));

    const float c0 = s0 + bv.x, c1 = s1 + bv.y, c2 = s2 + bv.z, c3 = s3 + bv.w;

    // lane-local top2 of 4
    float m1 = fmaxf(c0, c1), m2 = fminf(c0, c1);
    if (c2 > m1) { m2 = m1; m1 = c2; } else m2 = fmaxf(m2, c2);
    if (c3 > m1) { m2 = m1; m1 = c3; } else m2 = fmaxf(m2, c3);
#pragma unroll
    for (int off = 1; off < 8; off <<= 1) {
      const float o1 = __shfl_xor(m1, off);
      const float o2 = __shfl_xor(m2, off);
      if (o1 > m1) { m2 = fmaxf(m1, o2); m1 = o1; }
      else m2 = fmaxf(m2, o1);
    }
    const float gs = m1 + m2;  // group score (identical across the 8 lanes)

    const int gme = lane >> 3;
    int rank = 0;
#pragma unroll
    for (int j = 0; j < 8; ++j) {
      const float gj = __shfl(gs, j * 8);
      rank += ((gj > gs) || (gj == gs && j < gme)) ? 1 : 0;
    }
    const bool sel = rank < 4;

    const float NEG = -INFINITY;
    float q0 = sel ? c0 : NEG, q1 = sel ? c1 : NEG;
    float q2 = sel ? c2 : NEG, q3 = sel ? c3 : NEG;

    float sum = 0.f;
    int my_e = 0;
    float my_w = 0.f;
#pragma unroll
    for (int r = 0; r < 8; ++r) {
      float v = q0; int ix = 0;
      if (q1 > v) { v = q1; ix = 1; }
      if (q2 > v) { v = q2; ix = 2; }
      if (q3 > v) { v = q3; ix = 3; }
      int e = lane * 4 + ix;
#pragma unroll
      for (int off = 1; off < 64; off <<= 1) {
        const float v2 = __shfl_xor(v, off);
        const int e2 = __shfl_xor(e, off);
        const bool take = (v2 > v) || (v2 == v && e2 < e);
        v = take ? v2 : v;
        e = take ? e2 : e;
      }
      const int slot = e & 3, owner = e >> 2;
      const float svs = (slot == 0) ? s0 : ((slot == 1) ? s1 : ((slot == 2) ? s2 : s3));
      const float wgt = __shfl(svs, owner);
      sum += wgt;
      if (lane == r) { my_e = e; my_w = wgt; }
      const bool own = (lane == owner);
      q0 = (own && slot == 0) ? NEG : q0;
      q1 = (own && slot == 1) ? NEG : q1;
      q2 = (own && slot == 2) ? NEG : q2;
      q3 = (own && slot == 3) ? NEG : q3;
    }

    if (lane < 8) {
      const float denom = sum + 1e-20f;
      const long tg = bm0 + t;
      out[tg * 8 + lane] = (float)my_e;
      out[(long)T * 8 + tg * 8 + lane] = my_w / denom * 2.5f;
    }
  }
}

// ---------------------------------------------------------------------------
extern "C" void kernel_launch(void* const* d_in, const int* in_sizes, int n_in,
                              void* d_out, int out_size, void* d_ws, size_t ws_size,
                              hipStream_t stream) {
  const float* X = (const float*)d_in[0];   // [T, 4096]
  const float* W = (const float*)d_in[1];   // [256, 4096]
  const float* B = (const float*)d_in[2];   // [256]
  float* out = (float*)d_out;
  const int T = in_sizes[0] / Hdim;         // 16384

  _Float16* planes = (_Float16*)d_ws;       // 2 x 2 MB = 4 MB scratch

  convert_w<<<512, 256, 0, stream>>>(W, planes);
  moe_gate_fused<<<T / BM, 512, 0, stream>>>(X, planes, B, out, T);
}

// Round 12
// 165.131 us; speedup vs baseline: 2.0145x; 1.0352x over previous
//
#include <hip/hip_runtime.h>
#include <math.h>

#define Hdim 4096
#define NE 256
#define BM 32
#define BK 32
#define NKC (Hdim / BK)          // 128 K-chunks, 64 pairs
#define PLANE_ELEMS (Hdim * NE)  // f16 elements per plane (1,048,576 = 2 MB)
#define CHUNK_ELEMS 8192         // f16 elements per K-chunk image (16 KB)

// Scales (exact powers of two; undone in epilogue):
//   W' = 64*w, X' = 16*x, m-planes additionally *2048.
//   logit = (acc0 + acc1*2^-11) * 2^-10   (mm product dropped: validated R6-R11)
#define C0 9.765625e-4f            // 2^-10
#define C1 4.76837158203125e-7f    // 2^-21

typedef _Float16 f16x8 __attribute__((ext_vector_type(8)));
typedef _Float16 f16x4 __attribute__((ext_vector_type(4)));
typedef float f32x4 __attribute__((ext_vector_type(4)));

// ---------------------------------------------------------------------------
// W [256][4096] fp32 -> 2 f16 planes: h = f16(64w), m = f16((64w - h)*2048).
// Plane layout: [k8 0..511][n 0..255] chunks of 8 f16 (16 B): element (n,k)
// at plane + ((k/8)*256 + n)*8 + k%8 — 16 consecutive n are 256 B contiguous,
// so per-lane fragment loads below are coalesced (4 x 256 B per instruction).
// ---------------------------------------------------------------------------
__global__ __launch_bounds__(256)
void convert_w(const float* __restrict__ W, _Float16* __restrict__ pl) {
  const int id = blockIdx.x * 256 + threadIdx.x;  // 0 .. 131071
  const int k8 = id & 511;
  const int n = id >> 9;
  const float* src = W + (long)n * Hdim + k8 * 8;
  const float4 x0 = *(const float4*)src;
  const float4 x1 = *(const float4*)(src + 4);
  const float xv[8] = {x0.x, x0.y, x0.z, x0.w, x1.x, x1.y, x1.z, x1.w};
  f16x8 vh, vm;
#pragma unroll
  for (int j = 0; j < 8; ++j) {
    const float v = xv[j] * 64.f;
    const _Float16 h = (_Float16)v;
    const float r = (v - (float)h) * 2048.f;
    vh[j] = h;
    vm[j] = (_Float16)r;
  }
  const long co = ((long)k8 * NE + n) * 8;
  *(f16x8*)(pl + co) = vh;
  *(f16x8*)(pl + PLANE_ELEMS + co) = vm;
}

// ---------------------------------------------------------------------------
// Fused: logits = X @ W^T via 3-product split-f16 MFMA (hh, hm, mh), then
// top-k epilogue. R11-verified skeleton (X split-f16 in dbuf LDS, W fragments
// direct from ws planes into registers, 512 thr = 8 waves x (32 tok x 32 exp),
// 2 blk/CU / 16 waves/CU) coarsened to CHUNK-PAIR phases (64 K per barrier):
//   - X: both sub-chunks staged per phase by ALL 512 threads (1 float4 each,
//     same per-chunk layout at sub-chunk offset) -> 64 barriers (was 128),
//     staging instruction count halved.
//   - W: 4 register buffers (wA..wD); next pair's 8 loads issued before this
//     pair's 24 MFMAs -> ~2x L2-latency coverage.
// LDS 36 KB: X pair-bufs 2x8 KB @0; epilogue lg [32][260] f32 aliases smem.
// ---------------------------------------------------------------------------
__global__ __launch_bounds__(512, 4)
void moe_gate_fused(const float* __restrict__ X, const _Float16* __restrict__ pl,
                    const float* __restrict__ bias, float* __restrict__ out, int T) {
  __shared__ __align__(16) unsigned char smem[36864];
  const int tid = threadIdx.x;
  const int lane = tid & 63, wave = tid >> 6;      // wave = wn (0..7)
  const int r16 = lane & 15, c4 = lane >> 4;
  const long bm0 = (long)blockIdx.x * BM;

  f32x4 acc0[2][2], acc1[2][2];
#pragma unroll
  for (int i = 0; i < 2; ++i)
#pragma unroll
    for (int j = 0; j < 2; ++j) {
      acc0[i][j] = (f32x4)(0.f);
      acc1[i][j] = (f32x4)(0.f);
    }

  // X staging geometry: 512 threads -> (token xm 0..31, pair-slot xf 0..15)
  // sub-chunk sc = xf>>3, within-chunk float4 slot f4 = xf&7
  const int xm = tid >> 4;
  const int xf = tid & 15;
  const float* xsrc = X + (bm0 + xm) * (long)Hdim + xf * 4;  // + pair*64
  const int xws = (xf >> 3) * 4096 +                       // sub-chunk
                  (((xf & 7) >> 1) * 32 + xm) * 16 + (xf & 1) * 8;  // in-plane

  // per-lane W-fragment sources (chunk image offset (c4*256 + n)*8)
  const _Float16* wsrc0 = pl + ((size_t)(c4 * 256 + wave * 32 + r16)) * 8;
  const _Float16* wsrc1 = wsrc0 + PLANE_ELEMS;

  f16x8 wA[2][2], wB[2][2], wC[2][2], wD[2][2];   // [plane][fn]

#define LOADW(dst, kc_)                                                         \
  {                                                                             \
    const size_t ko = (size_t)(kc_) * CHUNK_ELEMS;                              \
    _Pragma("unroll") for (int fn = 0; fn < 2; ++fn) {                          \
      dst[0][fn] = *(const f16x8*)(wsrc0 + ko + fn * 128);                      \
      dst[1][fn] = *(const f16x8*)(wsrc1 + ko + fn * 128);                      \
    }                                                                           \
  }

#define WRITE_X2(b, xr)                                                         \
  {                                                                             \
    f16x4 vh, vm;                                                               \
    const float xa[4] = {(xr).x, (xr).y, (xr).z, (xr).w};                       \
    _Pragma("unroll") for (int j = 0; j < 4; ++j) {                             \
      const float v = xa[j] * 16.f;                                             \
      const _Float16 h = (_Float16)v;                                           \
      const float r = (v - (float)h) * 2048.f;                                  \
      vh[j] = h;                                                                \
      vm[j] = (_Float16)r;                                                      \
    }                                                                           \
    const int xo = (b) * 8192 + xws;                                            \
    *(f16x4*)&smem[xo] = vh;                                                    \
    *(f16x4*)&smem[xo + 2048] = vm;                                             \
  }

#define COMPUTE(b, sc, wreg)                                                    \
  {                                                                             \
    const int xo = (b) * 8192 + (sc) * 4096;                                    \
    f16x8 af[2][2];                                                             \
    _Pragma("unroll") for (int p = 0; p < 2; ++p)                               \
        _Pragma("unroll") for (int fm = 0; fm < 2; ++fm)                        \
            af[p][fm] = *(const f16x8*)&smem[xo + p * 2048 +                    \
                                             (c4 * 32 + fm * 16 + r16) * 16];   \
    _Pragma("unroll") for (int fm = 0; fm < 2; ++fm)                            \
        _Pragma("unroll") for (int fn = 0; fn < 2; ++fn) {                      \
      acc0[fm][fn] = __builtin_amdgcn_mfma_f32_16x16x32_f16(                    \
          af[0][fm], wreg[0][fn], acc0[fm][fn], 0, 0, 0);                       \
      f32x4 s = acc1[fm][fn];                                                   \
      s = __builtin_amdgcn_mfma_f32_16x16x32_f16(af[0][fm], wreg[1][fn], s, 0, 0, 0); \
      s = __builtin_amdgcn_mfma_f32_16x16x32_f16(af[1][fm], wreg[0][fn], s, 0, 0, 0); \
      acc1[fm][fn] = s;                                                         \
    }                                                                           \
  }

  // prologue: X pair 0 into buf 0; W chunks 0,1 into wA,wB
  {
    const float4 x0 = *(const float4*)(xsrc);
    WRITE_X2(0, x0);
  }
  LOADW(wA, 0);
  LOADW(wB, 1);
  __syncthreads();

  for (int p = 0; p < NKC / 2; p += 2) {
    {  // even pair p: buf0, wA/wB; prefetch X pair p+1 -> buf1, W -> wC,wD
      const float4 xn = *(const float4*)(xsrc + (size_t)(p + 1) * 64);
      LOADW(wC, 2 * p + 2);
      LOADW(wD, 2 * p + 3);
      COMPUTE(0, 0, wA);
      COMPUTE(0, 1, wB);
      WRITE_X2(1, xn);
      __syncthreads();
    }
    {  // odd pair p+1: buf1, wC/wD; prefetch pair p+2 (clamped tail)
      const int pn = (p + 2 < NKC / 2) ? p + 2 : NKC / 2 - 1;
      const float4 xn = *(const float4*)(xsrc + (size_t)pn * 64);
      LOADW(wA, 2 * pn);
      LOADW(wB, 2 * pn + 1);
      COMPUTE(1, 0, wC);
      COMPUTE(1, 1, wD);
      if (p + 2 < NKC / 2) WRITE_X2(0, xn);
      __syncthreads();
    }
  }

  // ---- epilogue: logits -> LDS [32][260] fp32, then fused top-k ----
  float* lg = (float*)smem;
#pragma unroll
  for (int fm = 0; fm < 2; ++fm)
#pragma unroll
    for (int fn = 0; fn < 2; ++fn)
#pragma unroll
      for (int r = 0; r < 4; ++r) {
        const int t = fm * 16 + c4 * 4 + r;
        const int n = wave * 32 + fn * 16 + r16;
        lg[t * 260 + n] = fmaf(acc1[fm][fn][r], C1, acc0[fm][fn][r] * C0);
      }
  __syncthreads();

  // phase 2 (verified rounds 1-11 logic): wave processes 4 tokens sequentially
  const float4 bv = *(const float4*)(bias + lane * 4);
  for (int i = 0; i < 4; ++i) {
    const int t = wave * 4 + i;
    const float4 lgv = *(const float4*)&lg[t * 260 + lane * 4];

    const float s0 = 1.f / (1.f + expf(-lgv.x));
    const float s1 = 1.f / (1.f + expf(-lgv.y));
    const float s2 = 1.f / (1.f + expf(-lgv.z));
    const float s3 = 1.f / (1.f + expf(-lgv.w));

    const float c0 = s0 + bv.x, c1 = s1 + bv.y, c2 = s2 + bv.z, c3 = s3 + bv.w;

    // lane-local top2 of 4
    float m1 = fmaxf(c0, c1), m2 = fminf(c0, c1);
    if (c2 > m1) { m2 = m1; m1 = c2; } else m2 = fmaxf(m2, c2);
    if (c3 > m1) { m2 = m1; m1 = c3; } else m2 = fmaxf(m2, c3);
#pragma unroll
    for (int off = 1; off < 8; off <<= 1) {
      const float o1 = __shfl_xor(m1, off);
      const float o2 = __shfl_xor(m2, off);
      if (o1 > m1) { m2 = fmaxf(m1, o2); m1 = o1; }
      else m2 = fmaxf(m2, o1);
    }
    const float gs = m1 + m2;  // group score (identical across the 8 lanes)

    const int gme = lane >> 3;
    int rank = 0;
#pragma unroll
    for (int j = 0; j < 8; ++j) {
      const float gj = __shfl(gs, j * 8);
      rank += ((gj > gs) || (gj == gs && j < gme)) ? 1 : 0;
    }
    const bool sel = rank < 4;

    const float NEG = -INFINITY;
    float q0 = sel ? c0 : NEG, q1 = sel ? c1 : NEG;
    float q2 = sel ? c2 : NEG, q3 = sel ? c3 : NEG;

    float sum = 0.f;
    int my_e = 0;
    float my_w = 0.f;
#pragma unroll
    for (int r = 0; r < 8; ++r) {
      float v = q0; int ix = 0;
      if (q1 > v) { v = q1; ix = 1; }
      if (q2 > v) { v = q2; ix = 2; }
      if (q3 > v) { v = q3; ix = 3; }
      int e = lane * 4 + ix;
#pragma unroll
      for (int off = 1; off < 64; off <<= 1) {
        const float v2 = __shfl_xor(v, off);
        const int e2 = __shfl_xor(e, off);
        const bool take = (v2 > v) || (v2 == v && e2 < e);
        v = take ? v2 : v;
        e = take ? e2 : e;
      }
      const int slot = e & 3, owner = e >> 2;
      const float svs = (slot == 0) ? s0 : ((slot == 1) ? s1 : ((slot == 2) ? s2 : s3));
      const float wgt = __shfl(svs, owner);
      sum += wgt;
      if (lane == r) { my_e = e; my_w = wgt; }
      const bool own = (lane == owner);
      q0 = (own && slot == 0) ? NEG : q0;
      q1 = (own && slot == 1) ? NEG : q1;
      q2 = (own && slot == 2) ? NEG : q2;
      q3 = (own && slot == 3) ? NEG : q3;
    }

    if (lane < 8) {
      const float denom = sum + 1e-20f;
      const long tg = bm0 + t;
      out[tg * 8 + lane] = (float)my_e;
      out[(long)T * 8 + tg * 8 + lane] = my_w / denom * 2.5f;
    }
  }
}

// ---------------------------------------------------------------------------
extern "C" void kernel_launch(void* const* d_in, const int* in_sizes, int n_in,
                              void* d_out, int out_size, void* d_ws, size_t ws_size,
                              hipStream_t stream) {
  const float* X = (const float*)d_in[0];   // [T, 4096]
  const float* W = (const float*)d_in[1];   // [256, 4096]
  const float* B = (const float*)d_in[2];   // [256]
  float* out = (float*)d_out;
  const int T = in_sizes[0] / Hdim;         // 16384

  _Float16* planes = (_Float16*)d_ws;       // 2 x 2 MB = 4 MB scratch

  convert_w<<<512, 256, 0, stream>>>(W, planes);
  moe_gate_fused<<<T / BM, 512, 0, stream>>>(X, planes, B, out, T);
}